// Round 1
// baseline (6833.511 us; speedup 1.0000x reference)
//
#include <hip/hip_runtime.h>

// CLIP ViT encoder forward, 12 layers, bf16 MFMA compute, fp32 residual stream.
// L=12, T=197, B=64, D=768, H=12, hd=64, FF=3072, M = T*B = 12608.

#define NLAYER 12
#define T_TOK 197
#define B_BATCH 64
#define D_MODEL 768
#define H_HEADS 12
#define FF_DIM 3072
#define M_ROWS (T_TOK * B_BATCH)   // 12608

typedef __attribute__((ext_vector_type(8))) short short8;   // 8 x bf16 raw bits (4 VGPRs)
typedef __attribute__((ext_vector_type(4))) float f32x4;    // MFMA accumulator

// ---- helpers ----------------------------------------------------------------

__device__ __forceinline__ unsigned short f2b(float f) {  // fp32 -> bf16 RNE
  unsigned u = __float_as_uint(f);
  u = u + 0x7fffu + ((u >> 16) & 1u);
  return (unsigned short)(u >> 16);
}

typedef const __attribute__((address_space(1))) void* as1_cvp;
typedef __attribute__((address_space(3))) void* as3_vp;

__device__ __forceinline__ void gl_lds16(const void* g, void* l) {
  // async global->LDS, 16B per lane; LDS dest = l + lane*16 (wave-uniform base)
  __builtin_amdgcn_global_load_lds((as1_cvp)g, (as3_vp)l, 16, 0, 0);
}

// ---- weight fp32 -> bf16 ----------------------------------------------------

__global__ __launch_bounds__(256) void cvt_kernel(const float* __restrict__ in,
                                                  unsigned short* __restrict__ out, int n) {
  int stride = gridDim.x * blockDim.x * 4;
  for (int i = (blockIdx.x * blockDim.x + threadIdx.x) * 4; i < n; i += stride) {
    float4 v = *(const float4*)(in + i);
    ushort4 o;
    o.x = f2b(v.x); o.y = f2b(v.y); o.z = f2b(v.z); o.w = f2b(v.w);
    *(ushort4*)(out + i) = o;
  }
}

// ---- layernorm: one wave per row (768 = 64 lanes x 12), bf16 out ------------

__global__ __launch_bounds__(256) void ln_kernel(const float* __restrict__ x,
                                                 const float* __restrict__ g,
                                                 const float* __restrict__ b,
                                                 unsigned short* __restrict__ out) {
  int row = blockIdx.x * 4 + (threadIdx.x >> 6);
  int lane = threadIdx.x & 63;
  if (row >= M_ROWS) return;
  const float* xr = x + (size_t)row * D_MODEL;
  float4 v0 = *(const float4*)(xr + lane * 4);
  float4 v1 = *(const float4*)(xr + 256 + lane * 4);
  float4 v2 = *(const float4*)(xr + 512 + lane * 4);
  float s  = v0.x + v0.y + v0.z + v0.w + v1.x + v1.y + v1.z + v1.w
           + v2.x + v2.y + v2.z + v2.w;
  float ss = v0.x*v0.x + v0.y*v0.y + v0.z*v0.z + v0.w*v0.w
           + v1.x*v1.x + v1.y*v1.y + v1.z*v1.z + v1.w*v1.w
           + v2.x*v2.x + v2.y*v2.y + v2.z*v2.z + v2.w*v2.w;
  #pragma unroll
  for (int m = 1; m < 64; m <<= 1) {
    s  += __shfl_xor(s, m, 64);
    ss += __shfl_xor(ss, m, 64);
  }
  float mu = s * (1.0f / 768.0f);
  float var = ss * (1.0f / 768.0f) - mu * mu;
  float rs = rsqrtf(var + 1e-5f);
  unsigned short* orow = out + (size_t)row * D_MODEL;
  #pragma unroll
  for (int c = 0; c < 3; c++) {
    int col = c * 256 + lane * 4;
    float4 v = (c == 0) ? v0 : (c == 1) ? v1 : v2;
    float4 gg = *(const float4*)(g + col);
    float4 bb = *(const float4*)(b + col);
    ushort4 o;
    o.x = f2b((v.x - mu) * rs * gg.x + bb.x);
    o.y = f2b((v.y - mu) * rs * gg.y + bb.y);
    o.z = f2b((v.z - mu) * rs * gg.z + bb.z);
    o.w = f2b((v.w - mu) * rs * gg.w + bb.w);
    *(ushort4*)(orow + col) = o;
  }
}

// ---- GEMM C[m,n] = sum_k A[m,k] * W[n,k] + bias[n]  (B^T form, m97 structure)
// BM=BN=128, BK=32, 256 thr (4 waves), each wave 64x64 (4x4 16x16x32 frags).

#define EPI_BF16 0
#define EPI_GELU 1
#define EPI_RESID 2

template <int EPI>
__global__ __launch_bounds__(256) void gemm_bt(const unsigned short* __restrict__ A,
                                               const unsigned short* __restrict__ B,
                                               const float* __restrict__ bias,
                                               const float* __restrict__ xsrc,
                                               unsigned short* __restrict__ obf,
                                               float* __restrict__ of32,
                                               int M, int N, int K) {
  __shared__ __align__(16) unsigned short As[128 * 32];
  __shared__ __align__(16) unsigned short Bs[128 * 32];
  int tid = threadIdx.x;
  int wid = tid >> 6, lane = tid & 63;
  int lo = lane & 15, hi = lane >> 4;
  int bm = blockIdx.x * 128, bn = blockIdx.y * 128;

  int r0 = tid >> 2, kc = (tid & 3) * 8;
  int ar0 = bm + r0;       if (ar0 > M - 1) ar0 = M - 1;
  int ar1 = bm + r0 + 64;  if (ar1 > M - 1) ar1 = M - 1;
  const unsigned short* a0 = A + (size_t)ar0 * K + kc;
  const unsigned short* a1 = A + (size_t)ar1 * K + kc;
  const unsigned short* b0 = B + (size_t)(bn + r0) * K + kc;
  const unsigned short* b1 = B + (size_t)(bn + r0 + 64) * K + kc;
  char* asb = (char*)As + wid * 1024;
  char* bsb = (char*)Bs + wid * 1024;

  int wm = (wid & 1) * 64, wn = (wid >> 1) * 64;
  f32x4 acc[4][4];
  #pragma unroll
  for (int i = 0; i < 4; i++)
    #pragma unroll
    for (int j = 0; j < 4; j++) acc[i][j] = (f32x4)0.0f;

  for (int kt = 0; kt < K; kt += 32) {
    gl_lds16(a0 + kt, asb);
    gl_lds16(a1 + kt, asb + 4096);
    gl_lds16(b0 + kt, bsb);
    gl_lds16(b1 + kt, bsb + 4096);
    __syncthreads();
    short8 af[4], bf[4];
    #pragma unroll
    for (int i = 0; i < 4; i++)
      af[i] = *(const short8*)((const char*)As + (wm + i * 16 + lo) * 64 + hi * 16);
    #pragma unroll
    for (int j = 0; j < 4; j++)
      bf[j] = *(const short8*)((const char*)Bs + (wn + j * 16 + lo) * 64 + hi * 16);
    #pragma unroll
    for (int i = 0; i < 4; i++)
      #pragma unroll
      for (int j = 0; j < 4; j++)
        acc[i][j] = __builtin_amdgcn_mfma_f32_16x16x32_bf16(af[i], bf[j], acc[i][j], 0, 0, 0);
    __syncthreads();
  }

  // epilogue: C/D layout col = lane&15, row = (lane>>4)*4 + reg  [m89-verified]
  #pragma unroll
  for (int j = 0; j < 4; j++) {
    int ng = bn + wn + j * 16 + lo;
    float bv = bias[ng];
    #pragma unroll
    for (int i = 0; i < 4; i++) {
      #pragma unroll
      for (int r = 0; r < 4; r++) {
        int mg = bm + wm + i * 16 + hi * 4 + r;
        if (mg < M) {
          float v = acc[i][j][r] + bv;
          if (EPI == EPI_GELU) v = v * (1.0f / (1.0f + __expf(-1.702f * v)));
          if (EPI == EPI_RESID) {
            size_t idx = (size_t)mg * N + ng;
            of32[idx] = xsrc[idx] + v;
          } else {
            obf[(size_t)mg * N + ng] = f2b(v);
          }
        }
      }
    }
  }
}

// ---- fused attention: one block per (b,h), 4 waves, q-tiles of 64 rows ------
// qkv layout: row (t*B + b), cols [0:768)=Q [768:1536)=K [1536:2304)=V, head-major.

__global__ __launch_bounds__(256) void attn_kernel(const unsigned short* __restrict__ qkv,
                                                   const float* __restrict__ masks,
                                                   unsigned short* __restrict__ out) {
  int b = blockIdx.x / H_HEADS, h = blockIdx.x % H_HEADS;
  __shared__ __align__(16) unsigned short Ks[208 * 72];       // K rows, stride 72 (bank-safe)
  __shared__ __align__(16) unsigned short Vt[64 * 232];       // V transposed [d][t], stride 232
  __shared__ __align__(16) unsigned short Ps[4][16 * 232];    // per-wave P, stride 232
  int tid = threadIdx.x, wid = tid >> 6, lane = tid & 63;
  int lo = lane & 15, hi = lane >> 4;

  // zero Vt (avoid NaN garbage in padded token columns)
  for (int e = tid; e < (64 * 232) / 8; e += 256)
    *(uint4*)((char*)Vt + e * 16) = make_uint4(0, 0, 0, 0);
  __syncthreads();
  // stage K rows [t][d], 16B chunks
  for (int e = tid; e < T_TOK * 8; e += 256) {
    int t = e >> 3, c = e & 7;
    const unsigned short* src = qkv + ((size_t)t * B_BATCH + b) * 2304 + 768 + h * 64 + c * 8;
    *(uint4*)((char*)Ks + t * 144 + c * 16) = *(const uint4*)src;
  }
  // stage V transposed: Vt[d][t]
  for (int e = tid; e < T_TOK * 64; e += 256) {
    int t = e >> 6, d = e & 63;
    Vt[d * 232 + t] = qkv[((size_t)t * B_BATCH + b) * 2304 + 1536 + h * 64 + d];
  }
  __syncthreads();

  unsigned short* Pw = (unsigned short*)Ps[wid];
  for (int qt = 0; qt < 4; qt++) {
    int qbase = qt * 64 + wid * 16;
    // Q fragments direct from global (reused across 13 n-tiles)
    int qr = qbase + lo; if (qr > T_TOK - 1) qr = T_TOK - 1;
    const unsigned short* qsrc = qkv + ((size_t)qr * B_BATCH + b) * 2304 + h * 64;
    short8 qf0 = *(const short8*)(qsrc + hi * 8);
    short8 qf1 = *(const short8*)(qsrc + 32 + hi * 8);

    f32x4 accs[13];
    #pragma unroll
    for (int nt = 0; nt < 13; nt++) accs[nt] = (f32x4)0.0f;
    #pragma unroll
    for (int nt = 0; nt < 13; nt++) {
      short8 kf0 = *(const short8*)((const char*)Ks + (nt * 16 + lo) * 144 + hi * 16);
      short8 kf1 = *(const short8*)((const char*)Ks + (nt * 16 + lo) * 144 + 64 + hi * 16);
      accs[nt] = __builtin_amdgcn_mfma_f32_16x16x32_bf16(qf0, kf0, accs[nt], 0, 0, 0);
      accs[nt] = __builtin_amdgcn_mfma_f32_16x16x32_bf16(qf1, kf1, accs[nt], 0, 0, 0);
    }

    // softmax over each of the 4 rows this lane holds (row = hi*4 + r, col = nt*16+lo)
    #pragma unroll
    for (int r = 0; r < 4; r++) {
      float sv[13];
      float m = -1e30f;
      #pragma unroll
      for (int nt = 0; nt < 13; nt++) {
        int col = nt * 16 + lo;
        float sval = (col < T_TOK) ? accs[nt][r] * 0.125f : -1e30f;
        sv[nt] = sval;
        m = fmaxf(m, sval);
      }
      #pragma unroll
      for (int mk = 1; mk < 16; mk <<= 1) m = fmaxf(m, __shfl_xor(m, mk, 64));
      float sum = 0.0f;
      #pragma unroll
      for (int nt = 0; nt < 13; nt++) { sv[nt] = __expf(sv[nt] - m); sum += sv[nt]; }
      #pragma unroll
      for (int mk = 1; mk < 16; mk <<= 1) sum += __shfl_xor(sum, mk, 64);
      float inv = 1.0f / sum;
      int qrow = qbase + hi * 4 + r;
      #pragma unroll
      for (int nt = 0; nt < 13; nt++) {
        int col = nt * 16 + lo;
        float p = sv[nt] * inv;
        // hook: CLS query attention to patches modulated by mask (post-softmax, no renorm)
        if (qrow == 0 && col >= 1 && col < T_TOK) p *= masks[b * (T_TOK - 1) + col - 1];
        Pw[(hi * 4 + r) * 232 + col] = f2b(p);
      }
      Pw[(hi * 4 + r) * 232 + 208 + lo] = 0;  // zero pad cols 208..223
    }

    // PV: O[q,d] = sum_k P[q,k] * V[k,d]
    f32x4 acco[4];
    #pragma unroll
    for (int dt = 0; dt < 4; dt++) acco[dt] = (f32x4)0.0f;
    #pragma unroll
    for (int ks = 0; ks < 7; ks++) {
      short8 pf = *(const short8*)((const char*)Pw + lo * 464 + ks * 64 + hi * 16);
      #pragma unroll
      for (int dt = 0; dt < 4; dt++) {
        short8 vf = *(const short8*)((const char*)Vt + (dt * 16 + lo) * 464 + ks * 64 + hi * 16);
        acco[dt] = __builtin_amdgcn_mfma_f32_16x16x32_bf16(pf, vf, acco[dt], 0, 0, 0);
      }
    }
    // store O -> (t, b, h*64 + d) bf16
    #pragma unroll
    for (int dt = 0; dt < 4; dt++) {
      #pragma unroll
      for (int r = 0; r < 4; r++) {
        int q = qbase + hi * 4 + r;
        if (q < T_TOK)
          out[((size_t)q * B_BATCH + b) * D_MODEL + h * 64 + dt * 16 + lo] = f2b(acco[dt][r]);
      }
    }
  }
}

// ---- launch -----------------------------------------------------------------

extern "C" void kernel_launch(void* const* d_in, const int* in_sizes, int n_in,
                              void* d_out, int out_size, void* d_ws, size_t ws_size,
                              hipStream_t stream) {
  const float* hiddens = (const float*)d_in[0];
  const float* masks   = (const float*)d_in[1];
  const float* qkv_w   = (const float*)d_in[2];
  const float* qkv_b   = (const float*)d_in[3];
  const float* out_w   = (const float*)d_in[4];
  const float* out_b   = (const float*)d_in[5];
  const float* ln1_g   = (const float*)d_in[6];
  const float* ln1_b   = (const float*)d_in[7];
  const float* ln2_g   = (const float*)d_in[8];
  const float* ln2_b   = (const float*)d_in[9];
  const float* mlp_w1  = (const float*)d_in[10];
  const float* mlp_b1  = (const float*)d_in[11];
  const float* mlp_w2  = (const float*)d_in[12];
  const float* mlp_b2  = (const float*)d_in[13];
  float* x = (float*)d_out;   // fp32 residual stream lives in d_out (updated in place)

  size_t off = 0;
  auto alloc = [&](size_t bytes) -> char* {
    char* p = (char*)d_ws + off;
    off += (bytes + 255) & ~(size_t)255;
    return p;
  };
  unsigned short* wqkv   = (unsigned short*)alloc((size_t)NLAYER * 2304 * 768 * 2);
  unsigned short* wout   = (unsigned short*)alloc((size_t)NLAYER * 768 * 768 * 2);
  unsigned short* wm1    = (unsigned short*)alloc((size_t)NLAYER * 3072 * 768 * 2);
  unsigned short* wm2    = (unsigned short*)alloc((size_t)NLAYER * 768 * 3072 * 2);
  unsigned short* h_bf   = (unsigned short*)alloc((size_t)M_ROWS * 768 * 2);
  unsigned short* big_bf = (unsigned short*)alloc((size_t)M_ROWS * 3072 * 2); // qkv (2304) / mlp hidden (3072)
  unsigned short* ao_bf  = (unsigned short*)alloc((size_t)M_ROWS * 768 * 2);

  cvt_kernel<<<2048, 256, 0, stream>>>(qkv_w,  wqkv, NLAYER * 2304 * 768);
  cvt_kernel<<<2048, 256, 0, stream>>>(out_w,  wout, NLAYER * 768 * 768);
  cvt_kernel<<<2048, 256, 0, stream>>>(mlp_w1, wm1,  NLAYER * 3072 * 768);
  cvt_kernel<<<2048, 256, 0, stream>>>(mlp_w2, wm2,  NLAYER * 768 * 3072);

  for (int l = 0; l < NLAYER; l++) {
    const float* xin = (l == 0) ? hiddens : x;
    // LN1
    ln_kernel<<<M_ROWS / 4, 256, 0, stream>>>(xin, ln1_g + l * 768, ln1_b + l * 768, h_bf);
    // QKV
    gemm_bt<EPI_BF16><<<dim3(99, 18), 256, 0, stream>>>(
        h_bf, wqkv + (size_t)l * 2304 * 768, qkv_b + l * 2304, nullptr,
        big_bf, nullptr, M_ROWS, 2304, 768);
    // attention
    attn_kernel<<<B_BATCH * H_HEADS, 256, 0, stream>>>(big_bf, masks, ao_bf);
    // proj + residual
    gemm_bt<EPI_RESID><<<dim3(99, 6), 256, 0, stream>>>(
        ao_bf, wout + (size_t)l * 768 * 768, out_b + l * 768, xin,
        nullptr, x, M_ROWS, 768, 768);
    // LN2
    ln_kernel<<<M_ROWS / 4, 256, 0, stream>>>(x, ln2_g + l * 768, ln2_b + l * 768, h_bf);
    // MLP1 + QuickGELU
    gemm_bt<EPI_GELU><<<dim3(99, 24), 256, 0, stream>>>(
        h_bf, wm1 + (size_t)l * 3072 * 768, mlp_b1 + l * 3072, nullptr,
        big_bf, nullptr, M_ROWS, 3072, 768);
    // MLP2 + residual
    gemm_bt<EPI_RESID><<<dim3(99, 6), 256, 0, stream>>>(
        big_bf, wm2 + (size_t)l * 768 * 3072, mlp_b2 + l * 768, x,
        nullptr, x, M_ROWS, 768, 3072);
  }
}